// Round 3
// baseline (190.808 us; speedup 1.0000x reference)
//
#include <hip/hip_runtime.h>
#include <hip/hip_bf16.h>

// Shapes: bz=32, rv_num=10, rv_len=128, in_feat=300, out_feat=128
// N = 320 reviews/side, tokens/side = 40960, M = 1280 tokens/sample.

#define K_FEAT 300
#define H 128
#define NTOK 40960
#define NREV 320
#define TOK_PER_SAMPLE 1280
#define TM 64                       // tokens per fc block (4 waves x 16 tokens)
#define FC_BLKS_PER_SIDE 640        // 40960/64
#define PSUM_GROUPS 2560            // 40960/16 per side (16-token granularity)
#define PSUM_PER_SAMPLE 80          // 1280/16
#define NCHUNK 10
#define WFRAG_ELEMS (NCHUNK * 4 * 4 * 64 * 8)   // 81920 bf16 = 160 KB

typedef __attribute__((ext_vector_type(8))) short bf16x8;
typedef __attribute__((ext_vector_type(4))) float f32x4;
typedef unsigned short u16;
typedef unsigned int u32;

static __device__ __forceinline__ u16 f2bf(float x) {
    u32 u = __float_as_uint(x);
    return (u16)((u + 0x7fffu + ((u >> 16) & 1u)) >> 16);
}
static __device__ __forceinline__ float bf2f(u16 s) {
    return __uint_as_float(((u32)s) << 16);
}

// ---------------- Kernel 0: pack W into per-(chunk,htile-pair,frag,lane) bf16 fragments ----
// Wfrag[c][p][frag][lane][8]; frag = t2*2 + part (part 0=hi, 1=lo).
// h = (2*p + t2)*16 + (lane&15); k = c*32 + (lane>>4)*8 + j; zero-pad k >= 300.
__global__ void wsplit_kernel(const float* __restrict__ W, u16* __restrict__ Wfrag)
{
    int i = blockIdx.x * 256 + threadIdx.x;
    if (i >= WFRAG_ELEMS) return;
    int j    = i & 7;
    int lane = (i >> 3) & 63;
    int frag = (i >> 9) & 3;
    int p    = (i >> 11) & 3;
    int c    = i >> 13;
    int nn = lane & 15, quad = lane >> 4;
    int t2 = frag >> 1, part = frag & 1;
    int h = (2 * p + t2) * 16 + nn;
    int k = c * 32 + quad * 8 + j;
    float w = (k < K_FEAT) ? W[(size_t)k * H + h] : 0.f;
    u16 hi = f2bf(w);
    Wfrag[i] = part ? f2bf(w - bf2f(hi)) : hi;
}

// Convert 8 consecutive f32 -> 8 bf16 hi + 8 bf16 lo, packed as two uint4 (16B each).
static __device__ __forceinline__ void cvt_pack(const float4 a, const float4 b,
                                                uint4& hp, uint4& lp)
{
    u16 h0 = f2bf(a.x), h1 = f2bf(a.y), h2 = f2bf(a.z), h3 = f2bf(a.w);
    u16 h4 = f2bf(b.x), h5 = f2bf(b.y), h6 = f2bf(b.z), h7 = f2bf(b.w);
    hp.x = (u32)h0 | ((u32)h1 << 16);
    hp.y = (u32)h2 | ((u32)h3 << 16);
    hp.z = (u32)h4 | ((u32)h5 << 16);
    hp.w = (u32)h6 | ((u32)h7 << 16);
    lp.x = (u32)f2bf(a.x - bf2f(h0)) | ((u32)f2bf(a.y - bf2f(h1)) << 16);
    lp.y = (u32)f2bf(a.z - bf2f(h2)) | ((u32)f2bf(a.w - bf2f(h3)) << 16);
    lp.z = (u32)f2bf(b.x - bf2f(h4)) | ((u32)f2bf(b.y - bf2f(h5)) << 16);
    lp.w = (u32)f2bf(b.z - bf2f(h6)) | ((u32)f2bf(b.w - bf2f(h7)) << 16);
}

// ---------------- Kernel 1: FC + ReLU — BARRIER-FREE per-wave design --------------------
// grid.x = 1280; block = 256 = 4 INDEPENDENT waves (zero __syncthreads).
// Each wave owns 16 tokens x all 128 h: stages its own A chunk (16 tok x 32 k, hi/lo)
// into its private LDS region (in-order DS per wave => no sync needed), then loops over
// all 4 h-tile-pairs of W (L1-hot, shared across all resident waves).
// A-fragment LDS reads: 2 per chunk, reused across all 8 h-tiles (4x fewer than before).
__global__ __launch_bounds__(256, 5) void fc_mfma_kernel(
    const float* __restrict__ seq_a, const float* __restrict__ seq_b,
    const u16* __restrict__ Wfrag, const float* __restrict__ bias,
    u16* __restrict__ ta, u16* __restrict__ tb,
    float* __restrict__ psum_a, float* __restrict__ psum_b)
{
    __shared__ __align__(16) u16 Ah_s[4][2][512];   // [wave][buf][frag elems]
    __shared__ __align__(16) u16 Al_s[4][2][512];

    int blk = blockIdx.x;
    const float* seq; u16* outp; float* psum;
    if (blk < FC_BLKS_PER_SIDE) { seq = seq_a; outp = ta; psum = psum_a; }
    else { seq = seq_b; outp = tb; psum = psum_b; blk -= FC_BLKS_PER_SIDE; }

    const int tid = threadIdx.x;
    const int wave = tid >> 6;
    const int lane = tid & 63;
    const int nn = lane & 15;
    const int quad = lane >> 4;
    const int tok0w = blk * TM + wave * 16;     // wave's 16 tokens

    // Staging: lane owns token ts (0..15), k-octet qs (0..3) of each 32-k chunk.
    const int ts = lane >> 2;
    const int qs = lane & 3;
    const float* srow = seq + (size_t)(tok0w + ts) * K_FEAT + qs * 8;
    const int stg = ((qs << 4) + ts) * 8;       // fragment-major position

    f32x4 acc[8];                               // one f32x4 per h-tile
#pragma unroll
    for (int t = 0; t < 8; ++t) acc[t] = (f32x4){0.f, 0.f, 0.f, 0.f};

#define LOADC(cc, x0, x1) do {                                                \
        if ((cc) < 9) { /* compile-time: always in-bounds for chunks 0..8 */  \
            x0 = *(const float4*)(srow + (cc) * 32);                          \
            x1 = *(const float4*)(srow + (cc) * 32 + 4);                      \
        } else {                                                              \
            int kb = (cc) * 32 + qs * 8;                                      \
            x0 = make_float4(0.f, 0.f, 0.f, 0.f);                             \
            x1 = make_float4(0.f, 0.f, 0.f, 0.f);                             \
            if (kb + 4 <= K_FEAT) x0 = *(const float4*)(srow + (cc) * 32);    \
            if (kb + 8 <= K_FEAT) x1 = *(const float4*)(srow + (cc) * 32 + 4);\
        }                                                                     \
    } while (0)

#define STOREC(bufi, x0, x1) do {                               \
        uint4 hp, lp;                                           \
        cvt_pack(x0, x1, hp, lp);                               \
        *(uint4*)&Ah_s[wave][bufi][stg] = hp;                   \
        *(uint4*)&Al_s[wave][bufi][stg] = lp;                   \
    } while (0)

    float4 a0, a1, b0, b1;              // two register chunk slots (even c / odd c)
    LOADC(0, a0, a1);
    LOADC(1, b0, b1);
    STOREC(0, a0, a1);
    // no barrier: in-order per-wave DS guarantees read-after-write consistency

#pragma unroll
    for (int c = 0; c < NCHUNK; ++c) {
        const int cur = c & 1;
        // Prefetch seq chunk c+2 into the register slot chunk c vacates.
        if (c + 2 < NCHUNK) {
            if ((c & 1) == 0) { LOADC(c + 2, a0, a1); }
            else              { LOADC(c + 2, b0, b1); }
        }
        // A fragments for chunk c (2 LDS reads, reused across all 8 h-tiles).
        bf16x8 a_hi = *(const bf16x8*)&Ah_s[wave][cur][lane * 8];
        bf16x8 a_lo = *(const bf16x8*)&Al_s[wave][cur][lane * 8];
        // Stage chunk c+1 into the other buffer (issued after the reads above;
        // different buffer, and next iteration's read follows in DS order).
        if (c + 1 < NCHUNK) {
            if ((c & 1) == 0) { STOREC(cur ^ 1, b0, b1); }
            else              { STOREC(cur ^ 1, a0, a1); }
        }
        // Full W sweep: 4 h-tile pairs, L1/L2-resident (16KB/chunk shared by all waves).
        const u16* wfc = Wfrag + (size_t)c * 8192;
#pragma unroll
        for (int p = 0; p < 4; ++p) {
            const u16* wf = wfc + p * 2048;
            bf16x8 bh0 = *(const bf16x8*)&wf[0 * 512 + lane * 8];
            bf16x8 bl0 = *(const bf16x8*)&wf[1 * 512 + lane * 8];
            bf16x8 bh1 = *(const bf16x8*)&wf[2 * 512 + lane * 8];
            bf16x8 bl1 = *(const bf16x8*)&wf[3 * 512 + lane * 8];
            // swapped: D[h][tok]
            acc[2 * p]     = __builtin_amdgcn_mfma_f32_16x16x32_bf16(bh0, a_hi, acc[2 * p], 0, 0, 0);
            acc[2 * p]     = __builtin_amdgcn_mfma_f32_16x16x32_bf16(bl0, a_hi, acc[2 * p], 0, 0, 0);
            acc[2 * p]     = __builtin_amdgcn_mfma_f32_16x16x32_bf16(bh0, a_lo, acc[2 * p], 0, 0, 0);
            acc[2 * p + 1] = __builtin_amdgcn_mfma_f32_16x16x32_bf16(bh1, a_hi, acc[2 * p + 1], 0, 0, 0);
            acc[2 * p + 1] = __builtin_amdgcn_mfma_f32_16x16x32_bf16(bl1, a_hi, acc[2 * p + 1], 0, 0, 0);
            acc[2 * p + 1] = __builtin_amdgcn_mfma_f32_16x16x32_bf16(bh1, a_lo, acc[2 * p + 1], 0, 0, 0);
        }
    }
#undef LOADC
#undef STOREC

    // Epilogue: lane holds h = ht*16 + quad*4 + r, tok = tok0w + nn. No barrier needed.
    const int g = blk * 4 + wave;               // 16-token psum group index
#pragma unroll
    for (int ht = 0; ht < 8; ++ht) {
        const int h0 = ht * 16 + quad * 4;
        const float4 bb = *(const float4*)&bias[h0];    // L1-hot global
        float v0 = fmaxf(acc[ht][0] + bb.x, 0.f);
        float v1 = fmaxf(acc[ht][1] + bb.y, 0.f);
        float v2 = fmaxf(acc[ht][2] + bb.z, 0.f);
        float v3 = fmaxf(acc[ht][3] + bb.w, 0.f);
        uint2 pk;
        pk.x = (u32)f2bf(v0) | ((u32)f2bf(v1) << 16);
        pk.y = (u32)f2bf(v2) | ((u32)f2bf(v3) << 16);
        *(uint2*)&outp[(size_t)(tok0w + nn) * H + h0] = pk;
        // reduce over nn (this wave's 16 tokens)
        float fs0 = v0, fs1 = v1, fs2 = v2, fs3 = v3;
#pragma unroll
        for (int x = 1; x < 16; x <<= 1) {
            fs0 += __shfl_xor(fs0, x);
            fs1 += __shfl_xor(fs1, x);
            fs2 += __shfl_xor(fs2, x);
            fs3 += __shfl_xor(fs3, x);
        }
        if (nn == 0) {
            psum[(size_t)g * H + h0 + 0] = fs0;
            psum[(size_t)g * H + h0 + 1] = fs1;
            psum[(size_t)g * H + h0 + 2] = fs2;
            psum[(size_t)g * H + h0 + 3] = fs3;
        }
    }
}

// ---------------- Kernel 2: scores -> masked softmax -> weighted sum (bf16 tiles) ----------
// grid.x = 640; block = 512.
__global__ __launch_bounds__(512) void attn_kernel(
    const u16* __restrict__ ta, const u16* __restrict__ tb,
    const int* __restrict__ mask_a, const int* __restrict__ mask_b,
    const float* __restrict__ psum_a, const float* __restrict__ psum_b,
    float* __restrict__ out)
{
    int n = blockIdx.x;
    int side = 0;
    if (n >= NREV) { side = 1; n -= NREV; }

    const u16* t = side ? tb : ta;
    const int* mask = side ? mask_b : mask_a;
    const float* psum_o = side ? psum_a : psum_b;   // partial sums of the OTHER side
    float* out_vec = out + (side ? NREV * H : 0);
    float* out_w = out + 2 * NREV * H + (side ? NREV * H : 0);

    int sample = n / 10;
    int tid = threadIdx.x;

    __shared__ float score_part[128 * 17];  // [row][col-group-of-8], padded
    __shared__ float mean_s[128];
    __shared__ float w_s[128];
    __shared__ float red[8];
    __shared__ float part_out[32 * 128];

    if (tid < 128) {
        const float* pb = psum_o + (size_t)sample * PSUM_PER_SAMPLE * H + tid;
        float s0 = 0.f, s1 = 0.f, s2 = 0.f, s3 = 0.f;
#pragma unroll
        for (int i = 0; i < PSUM_PER_SAMPLE; i += 4) {
            s0 += pb[(size_t)(i + 0) * H];
            s1 += pb[(size_t)(i + 1) * H];
            s2 += pb[(size_t)(i + 2) * H];
            s3 += pb[(size_t)(i + 3) * H];
        }
        mean_s[tid] = (s0 + s1 + s2 + s3) * (1.0f / (float)TOK_PER_SAMPLE);
    }
    __syncthreads();

    const u16* rowbase = t + (size_t)n * 128 * H;

    // Phase 1: streaming score partials; uint4 = 8 bf16 per load, coalesced.
#pragma unroll
    for (int i = 0; i < 4; ++i) {
        int q = tid + 512 * i;          // 0..2047
        int r = q >> 4;                 // row
        int c8 = q & 15;                // group of 8 features
        uint4 v = *(const uint4*)&rowbase[r * H + c8 * 8];
        const float* m = &mean_s[c8 * 8];
        float p = 0.f;
        p += bf2f((u16)(v.x & 0xffff)) * m[0];
        p += bf2f((u16)(v.x >> 16)) * m[1];
        p += bf2f((u16)(v.y & 0xffff)) * m[2];
        p += bf2f((u16)(v.y >> 16)) * m[3];
        p += bf2f((u16)(v.z & 0xffff)) * m[4];
        p += bf2f((u16)(v.z >> 16)) * m[5];
        p += bf2f((u16)(v.w & 0xffff)) * m[6];
        p += bf2f((u16)(v.w >> 16)) * m[7];
        score_part[r * 17 + c8] = p;
    }
    __syncthreads();

    // Phase 2: row sums -> masked softmax (waves 2..7 carry -1e9 / exp->0, harmless)
    float logit = -1e9f;
    if (tid < 128) {
        float s = 0.f;
#pragma unroll
        for (int j = 0; j < 16; ++j) s += score_part[tid * 17 + j];
        int mv = mask[n * 128 + tid];
        logit = (mv > 0) ? s : -1e9f;
    }

    float mx = logit;
    for (int off = 32; off > 0; off >>= 1) mx = fmaxf(mx, __shfl_xor(mx, off));
    if ((tid & 63) == 0) red[tid >> 6] = mx;
    __syncthreads();
    mx = red[0];
#pragma unroll
    for (int rr = 1; rr < 8; ++rr) mx = fmaxf(mx, red[rr]);
    __syncthreads();

    float e = __expf(logit - mx);
    float ssum = e;
    for (int off = 32; off > 0; off >>= 1) ssum += __shfl_xor(ssum, off);
    if ((tid & 63) == 0) red[tid >> 6] = ssum;
    __syncthreads();
    ssum = 0.f;
#pragma unroll
    for (int rr = 0; rr < 8; ++rr) ssum += red[rr];

    float w = e / ssum;
    if (tid < 128) {
        w_s[tid] = w;
        out_w[n * 128 + tid] = w;
    }
    __syncthreads();

    // Phase 3: out[d] = sum_l w_l * row_l[d] (rows L2-hot, bf16); 32 l-partitions.
    int c8 = tid & 15;   // 8 features
    int lp = tid >> 4;   // 32 l-partitions
    float o[8] = {0.f, 0.f, 0.f, 0.f, 0.f, 0.f, 0.f, 0.f};
#pragma unroll
    for (int k = 0; k < 4; ++k) {
        int l = k * 32 + lp;
        float wl = w_s[l];
        uint4 v = *(const uint4*)&rowbase[l * H + c8 * 8];
        o[0] = fmaf(wl, bf2f((u16)(v.x & 0xffff)), o[0]);
        o[1] = fmaf(wl, bf2f((u16)(v.x >> 16)), o[1]);
        o[2] = fmaf(wl, bf2f((u16)(v.y & 0xffff)), o[2]);
        o[3] = fmaf(wl, bf2f((u16)(v.y >> 16)), o[3]);
        o[4] = fmaf(wl, bf2f((u16)(v.z & 0xffff)), o[4]);
        o[5] = fmaf(wl, bf2f((u16)(v.z >> 16)), o[5]);
        o[6] = fmaf(wl, bf2f((u16)(v.w & 0xffff)), o[6]);
        o[7] = fmaf(wl, bf2f((u16)(v.w >> 16)), o[7]);
    }
    *(float4*)&part_out[lp * 128 + c8 * 8] = make_float4(o[0], o[1], o[2], o[3]);
    *(float4*)&part_out[lp * 128 + c8 * 8 + 4] = make_float4(o[4], o[5], o[6], o[7]);
    __syncthreads();
    if (tid < 128) {
        float s = 0.f;
#pragma unroll
        for (int p = 0; p < 32; ++p) s += part_out[p * 128 + tid];
        out_vec[n * 128 + tid] = s;
    }
}

// ---------------- Launch ----------------
extern "C" void kernel_launch(void* const* d_in, const int* in_sizes, int n_in,
                              void* d_out, int out_size, void* d_ws, size_t ws_size,
                              hipStream_t stream)
{
    const float* seq_a = (const float*)d_in[0];
    const float* seq_b = (const float*)d_in[1];
    const int* mask_a = (const int*)d_in[2];
    const int* mask_b = (const int*)d_in[3];
    const float* W = (const float*)d_in[4];
    const float* bias = (const float*)d_in[5];
    float* out = (float*)d_out;

    u16* ta = (u16*)d_ws;                             // 40960*128 bf16
    u16* tb = ta + (size_t)NTOK * H;                  // 40960*128 bf16
    float* psum_a = (float*)(tb + (size_t)NTOK * H);  // 2560*128 f32
    float* psum_b = psum_a + PSUM_GROUPS * H;         // 2560*128 f32
    u16* Wfrag = (u16*)(psum_b + PSUM_GROUPS * H);    // 81920 bf16

    wsplit_kernel<<<(WFRAG_ELEMS + 255) / 256, 256, 0, stream>>>(W, Wfrag);
    fc_mfma_kernel<<<2 * FC_BLKS_PER_SIDE, 256, 0, stream>>>(seq_a, seq_b, Wfrag, bias, ta, tb, psum_a, psum_b);
    attn_kernel<<<640, 512, 0, stream>>>(ta, tb, mask_a, mask_b, psum_a, psum_b, out);
}

// Round 4
// 151.499 us; speedup vs baseline: 1.2595x; 1.2595x over previous
//
#include <hip/hip_runtime.h>
#include <hip/hip_bf16.h>

// Shapes: bz=32, rv_num=10, rv_len=128, in_feat=300, out_feat=128
// N = 320 reviews/side, tokens/side = 40960, M = 1280 tokens/sample.

#define K_FEAT 300
#define H 128
#define NTOK 40960
#define NREV 320
#define TOK_PER_SAMPLE 1280
#define TM 64                       // tokens per fc block
#define FC_BLKS_PER_SIDE 640        // 40960/64
#define FC_BLKS_PER_SAMPLE 20       // 1280/64
#define NCHUNK 10
#define WFRAG_ELEMS (NCHUNK * 4 * 2 * 64 * 8)   // 40960 f16 = 80 KB

typedef _Float16 f16;
typedef __attribute__((ext_vector_type(8))) _Float16 f16x8;
typedef __attribute__((ext_vector_type(4))) float f32x4;
typedef unsigned short u16;
typedef unsigned int u32;

static __device__ __forceinline__ u16 f2bf(float x) {
    u32 u = __float_as_uint(x);
    return (u16)((u + 0x7fffu + ((u >> 16) & 1u)) >> 16);
}
static __device__ __forceinline__ float bf2f(u16 s) {
    return __uint_as_float(((u32)s) << 16);
}
static __device__ __forceinline__ u16 f2h_bits(float x) {
    f16 h = (f16)x;
    return *(u16*)&h;
}
static __device__ __forceinline__ u32 pk2h(float a, float b) {
    return (u32)f2h_bits(a) | ((u32)f2h_bits(b) << 16);
}

// ---------------- Kernel 0: pack W into f16 MFMA fragments --------------------------------
// Wfrag[c][p][t2][lane][8]; h = (2*p + t2)*16 + (lane&15); k = c*32 + (lane>>4)*8 + j.
// Zero-pad k >= 300. Single f16 term (no hi/lo split).
__global__ void wsplit_kernel(const float* __restrict__ W, u16* __restrict__ Wfrag)
{
    int i = blockIdx.x * 256 + threadIdx.x;
    if (i >= WFRAG_ELEMS) return;
    int j    = i & 7;
    int lane = (i >> 3) & 63;
    int t2   = (i >> 9) & 1;
    int p    = (i >> 10) & 3;
    int c    = i >> 12;
    int nn = lane & 15, quad = lane >> 4;
    int h = (2 * p + t2) * 16 + nn;
    int k = c * 32 + quad * 8 + j;
    float w = (k < K_FEAT) ? W[(size_t)k * H + h] : 0.f;
    Wfrag[i] = f2h_bits(w);
}

// ---------------- Kernel 1: FC + ReLU, single-term f16 MFMA, bf16 output ------------------
// grid.x = 1280 (5 blocks/CU); block = 256 (4 waves). Tile 64 tok x 128 feat.
// R1-proven ping-pong structure (ONE barrier per chunk), R2-verified fragment-major LDS.
// Per chunk per wave: 2 W loads (L2-hot), 4 A LDS reads, 8 MFMAs.
__global__ __launch_bounds__(256, 5) void fc_mfma_kernel(
    const float* __restrict__ seq_a, const float* __restrict__ seq_b,
    const u16* __restrict__ Wfrag, const float* __restrict__ bias,
    u16* __restrict__ ta, u16* __restrict__ tb,
    float* __restrict__ psum_a, float* __restrict__ psum_b)
{
    __shared__ __align__(16) u16 A_s[2][4 * 512];   // 2 x 4KB, fragment-major f16

    int blk = blockIdx.x;
    const float* seq; u16* outp; float* psum;
    if (blk < FC_BLKS_PER_SIDE) { seq = seq_a; outp = ta; psum = psum_a; }
    else { seq = seq_b; outp = tb; psum = psum_b; blk -= FC_BLKS_PER_SIDE; }

    const int tid = threadIdx.x;
    const int tok0 = blk * TM;
    const int wave = tid >> 6;
    const int lane = tid & 63;
    const int nn = lane & 15;
    const int quad = lane >> 4;

    // Staging: thread owns 8 consecutive k of one token.
    const int st_tok = tid >> 2;        // 0..63
    const int st_q = tid & 3;           // k-octet within chunk
    const float* srow = seq + (size_t)(tok0 + st_tok) * K_FEAT + st_q * 8;
    // fragment-major LDS offset (f16 units): m*512 + (q*16 + nn)*8
    const int stg = (st_tok >> 4) * 512 + ((st_q << 4) + (st_tok & 15)) * 8;

    f32x4 acc[4][2];                    // [tok-tile m][h-tile t2]
#pragma unroll
    for (int m = 0; m < 4; ++m) {
        acc[m][0] = (f32x4){0.f, 0.f, 0.f, 0.f};
        acc[m][1] = (f32x4){0.f, 0.f, 0.f, 0.f};
    }

#define LOADC(cc, x0, x1) do {                                                \
        if ((cc) < 9) { /* compile-time: chunks 0..8 fully in-bounds */       \
            x0 = *(const float4*)(srow + (cc) * 32);                          \
            x1 = *(const float4*)(srow + (cc) * 32 + 4);                      \
        } else {                                                              \
            int kb = (cc) * 32 + st_q * 8;                                    \
            x0 = make_float4(0.f, 0.f, 0.f, 0.f);                             \
            x1 = make_float4(0.f, 0.f, 0.f, 0.f);                             \
            if (kb + 4 <= K_FEAT) x0 = *(const float4*)(srow + (cc) * 32);    \
            if (kb + 8 <= K_FEAT) x1 = *(const float4*)(srow + (cc) * 32 + 4);\
        }                                                                     \
    } while (0)

#define STOREC(bufi, x0, x1) do {                               \
        uint4 pkt;                                              \
        pkt.x = pk2h(x0.x, x0.y);                               \
        pkt.y = pk2h(x0.z, x0.w);                               \
        pkt.z = pk2h(x1.x, x1.y);                               \
        pkt.w = pk2h(x1.z, x1.w);                               \
        *(uint4*)&A_s[bufi][stg] = pkt;                         \
    } while (0)

    float4 x0, x1;
    LOADC(0, x0, x1);
    STOREC(0, x0, x1);
    __syncthreads();

#pragma unroll
    for (int c = 0; c < NCHUNK; ++c) {
        const int cur = c & 1;
        // Issue seq loads for chunk c+1 (latency hidden behind MFMA section).
        if (c + 1 < NCHUNK) LOADC(c + 1, x0, x1);
        // W fragments for chunk c: 2 coalesced 16B loads (L2-resident, shared by all).
        const u16* wf = Wfrag + (size_t)c * 4096 + (size_t)wave * 1024;
        f16x8 wh0 = *(const f16x8*)&wf[0 * 512 + lane * 8];
        f16x8 wh1 = *(const f16x8*)&wf[1 * 512 + lane * 8];
#pragma unroll
        for (int m = 0; m < 4; ++m) {
            f16x8 a = *(const f16x8*)&A_s[cur][m * 512 + lane * 8];
            // swapped: D[h][tok]
            acc[m][0] = __builtin_amdgcn_mfma_f32_16x16x32_f16(wh0, a, acc[m][0], 0, 0, 0);
            acc[m][1] = __builtin_amdgcn_mfma_f32_16x16x32_f16(wh1, a, acc[m][1], 0, 0, 0);
        }
        // Stage chunk c+1 into the other buffer, then ONE barrier.
        if (c + 1 < NCHUNK) {
            STOREC(cur ^ 1, x0, x1);
            __syncthreads();
        }
    }
#undef LOADC
#undef STOREC

    // Epilogue: lane holds h = (2*wave+ht)*16 + quad*4 + r, tok = tok0 + m*16 + nn.
#pragma unroll
    for (int ht = 0; ht < 2; ++ht) {
        const int h0 = (2 * wave + ht) * 16 + quad * 4;
        const float4 bb = *(const float4*)&bias[h0];    // L1-hot global
        float fs[4] = {0.f, 0.f, 0.f, 0.f};
#pragma unroll
        for (int m = 0; m < 4; ++m) {
            int tok = tok0 + m * 16 + nn;
            float v0 = fmaxf(acc[m][ht][0] + bb.x, 0.f);
            float v1 = fmaxf(acc[m][ht][1] + bb.y, 0.f);
            float v2 = fmaxf(acc[m][ht][2] + bb.z, 0.f);
            float v3 = fmaxf(acc[m][ht][3] + bb.w, 0.f);
            fs[0] += v0; fs[1] += v1; fs[2] += v2; fs[3] += v3;
            uint2 pk;
            pk.x = (u32)f2bf(v0) | ((u32)f2bf(v1) << 16);
            pk.y = (u32)f2bf(v2) | ((u32)f2bf(v3) << 16);
            *(uint2*)&outp[(size_t)tok * H + h0] = pk;
        }
        // reduce over nn (16 tokens per tile x 4 tiles = all 64 tokens of the block)
#pragma unroll
        for (int r = 0; r < 4; ++r) {
            fs[r] += __shfl_xor(fs[r], 1);
            fs[r] += __shfl_xor(fs[r], 2);
            fs[r] += __shfl_xor(fs[r], 4);
            fs[r] += __shfl_xor(fs[r], 8);
        }
        if (nn == 0) {
#pragma unroll
            for (int r = 0; r < 4; ++r)
                psum[(size_t)blk * H + h0 + r] = fs[r];
        }
    }
}

// ---------------- Kernel 2: scores -> masked softmax -> weighted sum ----------------------
// grid.x = 640; block = 512. Rows staged into LDS during phase 1 (free — phase 1 loads
// them anyway); phase 3 reads LDS instead of re-reading 21 MB through L2/L3.
// score_part and part_out share one LDS region (disjoint live ranges, barrier-separated).
__global__ __launch_bounds__(512) void attn_kernel(
    const u16* __restrict__ ta, const u16* __restrict__ tb,
    const int* __restrict__ mask_a, const int* __restrict__ mask_b,
    const float* __restrict__ psum_a, const float* __restrict__ psum_b,
    float* __restrict__ out)
{
    int n = blockIdx.x;
    int side = 0;
    if (n >= NREV) { side = 1; n -= NREV; }

    const u16* t = side ? tb : ta;
    const int* mask = side ? mask_b : mask_a;
    const float* psum_o = side ? psum_a : psum_b;   // partial sums of the OTHER side
    float* out_vec = out + (side ? NREV * H : 0);
    float* out_w = out + 2 * NREV * H + (side ? NREV * H : 0);

    int sample = n / 10;
    int tid = threadIdx.x;

    __shared__ __align__(16) u16 T_s[128 * 128];    // 32 KB row cache (bf16 bits)
    __shared__ float fbuf[32 * 128];                // 16 KB: score_part then part_out
    __shared__ float mean_s[128];
    __shared__ float w_s[128];
    __shared__ float red[8];

    if (tid < 128) {
        float s = 0.f;
        const float* pb = psum_o + (size_t)sample * FC_BLKS_PER_SAMPLE * H + tid;
#pragma unroll
        for (int i = 0; i < FC_BLKS_PER_SAMPLE; ++i) s += pb[(size_t)i * H];
        mean_s[tid] = s * (1.0f / (float)TOK_PER_SAMPLE);
    }
    __syncthreads();

    const u16* rowbase = t + (size_t)n * 128 * H;

    // Phase 1: streaming score partials + LDS row staging; uint4 = 8 bf16 per load.
#pragma unroll
    for (int i = 0; i < 4; ++i) {
        int q = tid + 512 * i;          // 0..2047
        int r = q >> 4;                 // row
        int c8 = q & 15;                // group of 8 features
        uint4 v = *(const uint4*)&rowbase[r * H + c8 * 8];
        *(uint4*)&T_s[r * H + c8 * 8] = v;
        const float* m = &mean_s[c8 * 8];
        float p = 0.f;
        p += bf2f((u16)(v.x & 0xffff)) * m[0];
        p += bf2f((u16)(v.x >> 16)) * m[1];
        p += bf2f((u16)(v.y & 0xffff)) * m[2];
        p += bf2f((u16)(v.y >> 16)) * m[3];
        p += bf2f((u16)(v.z & 0xffff)) * m[4];
        p += bf2f((u16)(v.z >> 16)) * m[5];
        p += bf2f((u16)(v.w & 0xffff)) * m[6];
        p += bf2f((u16)(v.w >> 16)) * m[7];
        fbuf[r * 17 + c8] = p;          // score_part view
    }
    __syncthreads();

    // Phase 2: row sums -> masked softmax (threads >=128 carry -1e9 / exp->0, harmless)
    float logit = -1e9f;
    if (tid < 128) {
        float s = 0.f;
#pragma unroll
        for (int j = 0; j < 16; ++j) s += fbuf[tid * 17 + j];
        int mv = mask[n * 128 + tid];
        logit = (mv > 0) ? s : -1e9f;
    }

    float mx = logit;
    for (int off = 32; off > 0; off >>= 1) mx = fmaxf(mx, __shfl_xor(mx, off));
    if ((tid & 63) == 0) red[tid >> 6] = mx;
    __syncthreads();
    mx = red[0];
#pragma unroll
    for (int rr = 1; rr < 8; ++rr) mx = fmaxf(mx, red[rr]);
    __syncthreads();

    float e = __expf(logit - mx);
    float ssum = e;
    for (int off = 32; off > 0; off >>= 1) ssum += __shfl_xor(ssum, off);
    if ((tid & 63) == 0) red[tid >> 6] = ssum;
    __syncthreads();
    ssum = 0.f;
#pragma unroll
    for (int rr = 0; rr < 8; ++rr) ssum += red[rr];

    float w = e / ssum;
    if (tid < 128) {
        w_s[tid] = w;
        out_w[n * 128 + tid] = w;
    }
    __syncthreads();    // also separates score_part reads from part_out writes

    // Phase 3: out[d] = sum_l w_l * row_l[d] from LDS rows; 32 l-partitions.
    int c8 = tid & 15;   // 8 features
    int lp = tid >> 4;   // 32 l-partitions
    float o[8] = {0.f, 0.f, 0.f, 0.f, 0.f, 0.f, 0.f, 0.f};
#pragma unroll
    for (int k = 0; k < 4; ++k) {
        int l = k * 32 + lp;
        float wl = w_s[l];
        uint4 v = *(const uint4*)&T_s[l * H + c8 * 8];
        o[0] = fmaf(wl, bf2f((u16)(v.x & 0xffff)), o[0]);
        o[1] = fmaf(wl, bf2f((u16)(v.x >> 16)), o[1]);
        o[2] = fmaf(wl, bf2f((u16)(v.y & 0xffff)), o[2]);
        o[3] = fmaf(wl, bf2f((u16)(v.y >> 16)), o[3]);
        o[4] = fmaf(wl, bf2f((u16)(v.z & 0xffff)), o[4]);
        o[5] = fmaf(wl, bf2f((u16)(v.z >> 16)), o[5]);
        o[6] = fmaf(wl, bf2f((u16)(v.w & 0xffff)), o[6]);
        o[7] = fmaf(wl, bf2f((u16)(v.w >> 16)), o[7]);
    }
    *(float4*)&fbuf[lp * 128 + c8 * 8] = make_float4(o[0], o[1], o[2], o[3]);       // part_out view
    *(float4*)&fbuf[lp * 128 + c8 * 8 + 4] = make_float4(o[4], o[5], o[6], o[7]);
    __syncthreads();
    if (tid < 128) {
        float s = 0.f;
#pragma unroll
        for (int p = 0; p < 32; ++p) s += fbuf[p * 128 + tid];
        out_vec[n * 128 + tid] = s;
    }
}

// ---------------- Launch ----------------
extern "C" void kernel_launch(void* const* d_in, const int* in_sizes, int n_in,
                              void* d_out, int out_size, void* d_ws, size_t ws_size,
                              hipStream_t stream)
{
    const float* seq_a = (const float*)d_in[0];
    const float* seq_b = (const float*)d_in[1];
    const int* mask_a = (const int*)d_in[2];
    const int* mask_b = (const int*)d_in[3];
    const float* W = (const float*)d_in[4];
    const float* bias = (const float*)d_in[5];
    float* out = (float*)d_out;

    u16* ta = (u16*)d_ws;                             // 40960*128 bf16
    u16* tb = ta + (size_t)NTOK * H;                  // 40960*128 bf16
    float* psum_a = (float*)(tb + (size_t)NTOK * H);  // 640*128 f32
    float* psum_b = psum_a + FC_BLKS_PER_SIDE * H;    // 640*128 f32
    u16* Wfrag = (u16*)(psum_b + FC_BLKS_PER_SIDE * H); // 40960 f16

    wsplit_kernel<<<(WFRAG_ELEMS + 255) / 256, 256, 0, stream>>>(W, Wfrag);
    fc_mfma_kernel<<<2 * FC_BLKS_PER_SIDE, 256, 0, stream>>>(seq_a, seq_b, Wfrag, bias, ta, tb, psum_a, psum_b);
    attn_kernel<<<640, 512, 0, stream>>>(ta, tb, mask_a, mask_b, psum_a, psum_b, out);
}

// Round 6
// 144.603 us; speedup vs baseline: 1.3195x; 1.0477x over previous
//
#include <hip/hip_runtime.h>
#include <hip/hip_bf16.h>

// Shapes: bz=32, rv_num=10, rv_len=128, in_feat=300, out_feat=128
// N = 320 reviews/side, tokens/side = 40960, M = 1280 tokens/sample.

#define K_FEAT 300
#define H 128
#define NTOK 40960
#define NREV 320
#define TOK_PER_SAMPLE 1280
#define TM 64                       // tokens per fc block
#define FC_BLKS_PER_SIDE 640        // 40960/64
#define FC_BLKS_PER_SAMPLE 20       // 1280/64
#define NCHUNK 10
#define WFRAG_ELEMS (NCHUNK * 4 * 2 * 64 * 8)   // 40960 f16 = 80 KB

typedef _Float16 f16;
typedef __attribute__((ext_vector_type(8))) _Float16 f16x8;
typedef __attribute__((ext_vector_type(4))) float f32x4;
typedef unsigned short u16;
typedef unsigned int u32;

static __device__ __forceinline__ u16 f2bf(float x) {
    u32 u = __float_as_uint(x);
    return (u16)((u + 0x7fffu + ((u >> 16) & 1u)) >> 16);
}
static __device__ __forceinline__ float bf2f(u16 s) {
    return __uint_as_float(((u32)s) << 16);
}
static __device__ __forceinline__ u16 f2h_bits(float x) {
    f16 h = (f16)x;
    return *(u16*)&h;
}
static __device__ __forceinline__ u32 pk2h(float a, float b) {
    return (u32)f2h_bits(a) | ((u32)f2h_bits(b) << 16);
}

// ---------------- Kernel 0: pack W into f16 MFMA fragments --------------------------------
// Wfrag[c][p][t2][lane][8]; h = (2*p + t2)*16 + (lane&15); k = c*32 + (lane>>4)*8 + j.
// Zero-pad k >= 300. Single f16 term (no hi/lo split).
__global__ void wsplit_kernel(const float* __restrict__ W, u16* __restrict__ Wfrag)
{
    int i = blockIdx.x * 256 + threadIdx.x;
    if (i >= WFRAG_ELEMS) return;
    int j    = i & 7;
    int lane = (i >> 3) & 63;
    int t2   = (i >> 9) & 1;
    int p    = (i >> 10) & 3;
    int c    = i >> 12;
    int nn = lane & 15, quad = lane >> 4;
    int h = (2 * p + t2) * 16 + nn;
    int k = c * 32 + quad * 8 + j;
    float w = (k < K_FEAT) ? W[(size_t)k * H + h] : 0.f;
    Wfrag[i] = f2h_bits(w);
}

// ---------------- Kernel 1: FC + ReLU, single-term f16 MFMA, bf16 output ------------------
// grid.x = 1280; block = 256 (4 waves). Tile 64 tok x 128 feat.
// ONE barrier total: stage the ENTIRE 64x320 A-tile (f16 fragment-major, 40 KB LDS =
// 4 blocks/CU), then a fully-unrolled barrier-free MFMA sweep.
// Staging uses a DEPTH-3 rolling register pipeline (6 float4 = 24 VGPRs live, no spill;
// R5's 20-deep version spilled to scratch and aborted under graph capture).
__global__ __launch_bounds__(256, 4) void fc_mfma_kernel(
    const float* __restrict__ seq_a, const float* __restrict__ seq_b,
    const u16* __restrict__ Wfrag, const float* __restrict__ bias,
    u16* __restrict__ ta, u16* __restrict__ tb,
    float* __restrict__ psum_a, float* __restrict__ psum_b)
{
    __shared__ __align__(16) u16 A_s[NCHUNK * 4 * 512];   // 40960 B, fragment-major f16

    int blk = blockIdx.x;
    const float* seq; u16* outp; float* psum;
    if (blk < FC_BLKS_PER_SIDE) { seq = seq_a; outp = ta; psum = psum_a; }
    else { seq = seq_b; outp = tb; psum = psum_b; blk -= FC_BLKS_PER_SIDE; }

    const int tid = threadIdx.x;
    const int tok0 = blk * TM;
    const int wave = tid >> 6;
    const int lane = tid & 63;
    const int nn = lane & 15;
    const int quad = lane >> 4;

    // Staging: thread owns 8 consecutive k of one token, per chunk.
    const int st_tok = tid >> 2;        // 0..63
    const int st_q = tid & 3;           // k-octet within chunk
    const float* srow = seq + (size_t)(tok0 + st_tok) * K_FEAT + st_q * 8;
    // fragment-major LDS offset (f16 units): c*2048 + m*512 + (q*16 + nn)*8
    const int stg = (st_tok >> 4) * 512 + ((st_q << 4) + (st_tok & 15)) * 8;

#define LOADC(cc, x0, x1) do {                                                \
        if ((cc) < 9) { /* compile-time: chunks 0..8 fully in-bounds */       \
            x0 = *(const float4*)(srow + (cc) * 32);                          \
            x1 = *(const float4*)(srow + (cc) * 32 + 4);                      \
        } else {                                                              \
            int kb = (cc) * 32 + st_q * 8;                                    \
            x0 = make_float4(0.f, 0.f, 0.f, 0.f);                             \
            x1 = make_float4(0.f, 0.f, 0.f, 0.f);                             \
            if (kb + 4 <= K_FEAT) x0 = *(const float4*)(srow + (cc) * 32);    \
            if (kb + 8 <= K_FEAT) x1 = *(const float4*)(srow + (cc) * 32 + 4);\
        }                                                                     \
    } while (0)

#define STOREC(cc, x0, x1) do {                                 \
        uint4 pkt;                                              \
        pkt.x = pk2h(x0.x, x0.y);                               \
        pkt.y = pk2h(x0.z, x0.w);                               \
        pkt.z = pk2h(x1.x, x1.y);                               \
        pkt.w = pk2h(x1.z, x1.w);                               \
        *(uint4*)&A_s[(cc) * 2048 + stg] = pkt;                 \
    } while (0)

    // Phase 1: depth-3 rolling pipeline — 3 chunk-loads in flight, bounded registers.
    {
        float4 p0[3], p1[3];
        LOADC(0, p0[0], p1[0]);
        LOADC(1, p0[1], p1[1]);
        LOADC(2, p0[2], p1[2]);
#pragma unroll
        for (int c = 0; c < NCHUNK; ++c) {
            const int s = c % 3;                    // compile-time after unroll
            STOREC(c, p0[s], p1[s]);                // drains its own load (vmcnt)
            if (c + 3 < NCHUNK) LOADC(c + 3, p0[s], p1[s]);
        }
    }
    __syncthreads();    // the ONLY barrier in this kernel
#undef LOADC
#undef STOREC

    f32x4 acc[4][2];                    // [tok-tile m][h-tile t2]
#pragma unroll
    for (int m = 0; m < 4; ++m) {
        acc[m][0] = (f32x4){0.f, 0.f, 0.f, 0.f};
        acc[m][1] = (f32x4){0.f, 0.f, 0.f, 0.f};
    }

    // Phase 2: barrier-free MFMA sweep. Per chunk: 2 W loads (L2-hot, shared by all
    // resident waves), 4 A ds_reads, 8 MFMAs. Fully unrolled; waves free-run.
#pragma unroll
    for (int c = 0; c < NCHUNK; ++c) {
        const u16* wf = Wfrag + (size_t)c * 4096 + (size_t)wave * 1024;
        f16x8 wh0 = *(const f16x8*)&wf[0 * 512 + lane * 8];
        f16x8 wh1 = *(const f16x8*)&wf[1 * 512 + lane * 8];
#pragma unroll
        for (int m = 0; m < 4; ++m) {
            f16x8 a = *(const f16x8*)&A_s[c * 2048 + m * 512 + lane * 8];
            // swapped: D[h][tok]
            acc[m][0] = __builtin_amdgcn_mfma_f32_16x16x32_f16(wh0, a, acc[m][0], 0, 0, 0);
            acc[m][1] = __builtin_amdgcn_mfma_f32_16x16x32_f16(wh1, a, acc[m][1], 0, 0, 0);
        }
    }

    // Epilogue: lane holds h = (2*wave+ht)*16 + quad*4 + r, tok = tok0 + m*16 + nn.
#pragma unroll
    for (int ht = 0; ht < 2; ++ht) {
        const int h0 = (2 * wave + ht) * 16 + quad * 4;
        const float4 bb = *(const float4*)&bias[h0];    // L1-hot global
        float fs[4] = {0.f, 0.f, 0.f, 0.f};
#pragma unroll
        for (int m = 0; m < 4; ++m) {
            int tok = tok0 + m * 16 + nn;
            float v0 = fmaxf(acc[m][ht][0] + bb.x, 0.f);
            float v1 = fmaxf(acc[m][ht][1] + bb.y, 0.f);
            float v2 = fmaxf(acc[m][ht][2] + bb.z, 0.f);
            float v3 = fmaxf(acc[m][ht][3] + bb.w, 0.f);
            fs[0] += v0; fs[1] += v1; fs[2] += v2; fs[3] += v3;
            uint2 pk;
            pk.x = (u32)f2bf(v0) | ((u32)f2bf(v1) << 16);
            pk.y = (u32)f2bf(v2) | ((u32)f2bf(v3) << 16);
            *(uint2*)&outp[(size_t)tok * H + h0] = pk;
        }
        // reduce over nn (16 tokens per tile x 4 tiles = all 64 tokens of the block)
#pragma unroll
        for (int r = 0; r < 4; ++r) {
            fs[r] += __shfl_xor(fs[r], 1);
            fs[r] += __shfl_xor(fs[r], 2);
            fs[r] += __shfl_xor(fs[r], 4);
            fs[r] += __shfl_xor(fs[r], 8);
        }
        if (nn == 0) {
#pragma unroll
            for (int r = 0; r < 4; ++r)
                psum[(size_t)blk * H + h0 + r] = fs[r];
        }
    }
}

// ---------------- Kernel 2: scores -> masked softmax -> weighted sum ----------------------
// grid.x = 640; block = 512. Rows staged into LDS during phase 1 (free — phase 1 loads
// them anyway); phase 3 reads LDS instead of re-reading 21 MB through L2/L3.
__global__ __launch_bounds__(512) void attn_kernel(
    const u16* __restrict__ ta, const u16* __restrict__ tb,
    const int* __restrict__ mask_a, const int* __restrict__ mask_b,
    const float* __restrict__ psum_a, const float* __restrict__ psum_b,
    float* __restrict__ out)
{
    int n = blockIdx.x;
    int side = 0;
    if (n >= NREV) { side = 1; n -= NREV; }

    const u16* t = side ? tb : ta;
    const int* mask = side ? mask_b : mask_a;
    const float* psum_o = side ? psum_a : psum_b;   // partial sums of the OTHER side
    float* out_vec = out + (side ? NREV * H : 0);
    float* out_w = out + 2 * NREV * H + (side ? NREV * H : 0);

    int sample = n / 10;
    int tid = threadIdx.x;

    __shared__ __align__(16) u16 T_s[128 * 128];    // 32 KB row cache (bf16 bits)
    __shared__ float fbuf[32 * 128];                // 16 KB: score_part then part_out
    __shared__ float mean_s[128];
    __shared__ float w_s[128];
    __shared__ float red[8];

    if (tid < 128) {
        float s = 0.f;
        const float* pb = psum_o + (size_t)sample * FC_BLKS_PER_SAMPLE * H + tid;
#pragma unroll
        for (int i = 0; i < FC_BLKS_PER_SAMPLE; ++i) s += pb[(size_t)i * H];
        mean_s[tid] = s * (1.0f / (float)TOK_PER_SAMPLE);
    }
    __syncthreads();

    const u16* rowbase = t + (size_t)n * 128 * H;

    // Phase 1: streaming score partials + LDS row staging; uint4 = 8 bf16 per load.
#pragma unroll
    for (int i = 0; i < 4; ++i) {
        int q = tid + 512 * i;          // 0..2047
        int r = q >> 4;                 // row
        int c8 = q & 15;                // group of 8 features
        uint4 v = *(const uint4*)&rowbase[r * H + c8 * 8];
        *(uint4*)&T_s[r * H + c8 * 8] = v;
        const float* m = &mean_s[c8 * 8];
        float p = 0.f;
        p += bf2f((u16)(v.x & 0xffff)) * m[0];
        p += bf2f((u16)(v.x >> 16)) * m[1];
        p += bf2f((u16)(v.y & 0xffff)) * m[2];
        p += bf2f((u16)(v.y >> 16)) * m[3];
        p += bf2f((u16)(v.z & 0xffff)) * m[4];
        p += bf2f((u16)(v.z >> 16)) * m[5];
        p += bf2f((u16)(v.w & 0xffff)) * m[6];
        p += bf2f((u16)(v.w >> 16)) * m[7];
        fbuf[r * 17 + c8] = p;          // score_part view
    }
    __syncthreads();

    // Phase 2: row sums -> masked softmax (threads >=128 carry -1e9 / exp->0, harmless)
    float logit = -1e9f;
    if (tid < 128) {
        float s = 0.f;
#pragma unroll
        for (int j = 0; j < 16; ++j) s += fbuf[tid * 17 + j];
        int mv = mask[n * 128 + tid];
        logit = (mv > 0) ? s : -1e9f;
    }

    float mx = logit;
    for (int off = 32; off > 0; off >>= 1) mx = fmaxf(mx, __shfl_xor(mx, off));
    if ((tid & 63) == 0) red[tid >> 6] = mx;
    __syncthreads();
    mx = red[0];
#pragma unroll
    for (int rr = 1; rr < 8; ++rr) mx = fmaxf(mx, red[rr]);
    __syncthreads();

    float e = __expf(logit - mx);
    float ssum = e;
    for (int off = 32; off > 0; off >>= 1) ssum += __shfl_xor(ssum, off);
    if ((tid & 63) == 0) red[tid >> 6] = ssum;
    __syncthreads();
    ssum = 0.f;
#pragma unroll
    for (int rr = 0; rr < 8; ++rr) ssum += red[rr];

    float w = e / ssum;
    if (tid < 128) {
        w_s[tid] = w;
        out_w[n * 128 + tid] = w;
    }
    __syncthreads();    // also separates score_part reads from part_out writes

    // Phase 3: out[d] = sum_l w_l * row_l[d] from LDS rows; 32 l-partitions.
    int c8 = tid & 15;   // 8 features
    int lp = tid >> 4;   // 32 l-partitions
    float o[8] = {0.f, 0.f, 0.f, 0.f, 0.f, 0.f, 0.f, 0.f};
#pragma unroll
    for (int k = 0; k < 4; ++k) {
        int l = k * 32 + lp;
        float wl = w_s[l];
        uint4 v = *(const uint4*)&T_s[l * H + c8 * 8];
        o[0] = fmaf(wl, bf2f((u16)(v.x & 0xffff)), o[0]);
        o[1] = fmaf(wl, bf2f((u16)(v.x >> 16)), o[1]);
        o[2] = fmaf(wl, bf2f((u16)(v.y & 0xffff)), o[2]);
        o[3] = fmaf(wl, bf2f((u16)(v.y >> 16)), o[3]);
        o[4] = fmaf(wl, bf2f((u16)(v.z & 0xffff)), o[4]);
        o[5] = fmaf(wl, bf2f((u16)(v.z >> 16)), o[5]);
        o[6] = fmaf(wl, bf2f((u16)(v.w & 0xffff)), o[6]);
        o[7] = fmaf(wl, bf2f((u16)(v.w >> 16)), o[7]);
    }
    *(float4*)&fbuf[lp * 128 + c8 * 8] = make_float4(o[0], o[1], o[2], o[3]);       // part_out view
    *(float4*)&fbuf[lp * 128 + c8 * 8 + 4] = make_float4(o[4], o[5], o[6], o[7]);
    __syncthreads();
    if (tid < 128) {
        float s = 0.f;
#pragma unroll
        for (int p = 0; p < 32; ++p) s += fbuf[p * 128 + tid];
        out_vec[n * 128 + tid] = s;
    }
}

// ---------------- Launch ----------------
extern "C" void kernel_launch(void* const* d_in, const int* in_sizes, int n_in,
                              void* d_out, int out_size, void* d_ws, size_t ws_size,
                              hipStream_t stream)
{
    const float* seq_a = (const float*)d_in[0];
    const float* seq_b = (const float*)d_in[1];
    const int* mask_a = (const int*)d_in[2];
    const int* mask_b = (const int*)d_in[3];
    const float* W = (const float*)d_in[4];
    const float* bias = (const float*)d_in[5];
    float* out = (float*)d_out;

    u16* ta = (u16*)d_ws;                             // 40960*128 bf16
    u16* tb = ta + (size_t)NTOK * H;                  // 40960*128 bf16
    float* psum_a = (float*)(tb + (size_t)NTOK * H);  // 640*128 f32
    float* psum_b = psum_a + FC_BLKS_PER_SIDE * H;    // 640*128 f32
    u16* Wfrag = (u16*)(psum_b + FC_BLKS_PER_SIDE * H); // 40960 f16

    wsplit_kernel<<<(WFRAG_ELEMS + 255) / 256, 256, 0, stream>>>(W, Wfrag);
    fc_mfma_kernel<<<2 * FC_BLKS_PER_SIDE, 256, 0, stream>>>(seq_a, seq_b, Wfrag, bias, ta, tb, psum_a, psum_b);
    attn_kernel<<<640, 512, 0, stream>>>(ta, tb, mask_a, mask_b, psum_a, psum_b, out);
}